// Round 3
// baseline (1490.070 us; speedup 1.0000x reference)
//
#include <hip/hip_runtime.h>
#include <hip/hip_bf16.h>

#define N_USER 100000
#define N_PHOTO 200000
#define NEDGE 1000000
#define INF 256
#define OUTF 64

typedef unsigned short u16;
typedef __attribute__((ext_vector_type(8))) short short8;
typedef __attribute__((ext_vector_type(4))) float f32x4;

#define LDSPAD 264  // 256 + 8 pad: keeps 16B alignment, breaks pow2 bank stride

// f32 -> bf16 bits, round-to-nearest-even
__device__ inline u16 f2b(float f) {
    union { float f; unsigned u; } v; v.f = f;
    unsigned r = v.u + 0x7FFF + ((v.u >> 16) & 1);
    return (u16)(r >> 16);
}

// ---- W[256][64] f32 -> Wt[64][256] bf16 ----
__global__ __launch_bounds__(256) void transpose_w(const float* __restrict__ W,
                                                   u16* __restrict__ Wt) {
    int idx = blockIdx.x * 256 + threadIdx.x;   // 16384 total
    if (idx < INF * OUTF) {
        int n = idx & (OUTF - 1);
        int k = idx >> 6;
        Wt[n * INF + k] = f2b(W[idx]);
    }
}

// ---- Wh = feats @ W + b; f32 feats in, bf16 MFMA, bf16 Wh out ----
// 256 thr = 4 waves; wave does 16 rows x 64 cols; block does 64 rows
__global__ __launch_bounds__(256) void proj_gemm(const float* __restrict__ feats,
                                                 const u16* __restrict__ Wt,
                                                 const float* __restrict__ bias,
                                                 u16* __restrict__ Wh,
                                                 int nrows) {
    __shared__ u16 lds_wt[OUTF * LDSPAD];   // 33792 B
    int tid = threadIdx.x;
    for (int c = tid; c < (INF * OUTF) / 8; c += 256) {
        int n = c >> 5;
        int ko = (c & 31) * 8;
        *(short8*)&lds_wt[n * LDSPAD + ko] = *(const short8*)&Wt[n * INF + ko];
    }
    __syncthreads();

    int wave = tid >> 6, lane = tid & 63;
    int l15 = lane & 15, quad = lane >> 4;
    int r0 = blockIdx.x * 64 + wave * 16;
    int arow = r0 + l15;
    bool arow_ok = arow < nrows;

    f32x4 acc[4] = {{0,0,0,0},{0,0,0,0},{0,0,0,0},{0,0,0,0}};
    const float4* ap = (const float4*)(feats + (size_t)(arow_ok ? arow : 0) * INF);

    #pragma unroll
    for (int ks = 0; ks < 8; ++ks) {
        // A[m=arow][k=ks*32+quad*8+j], j=0..7 : two float4 loads, convert to bf16
        float4 x = ap[ks * 8 + quad * 2 + 0];
        float4 y = ap[ks * 8 + quad * 2 + 1];
        short8 a = { (short)f2b(x.x), (short)f2b(x.y), (short)f2b(x.z), (short)f2b(x.w),
                     (short)f2b(y.x), (short)f2b(y.y), (short)f2b(y.z), (short)f2b(y.w) };
        #pragma unroll
        for (int nt = 0; nt < 4; ++nt) {
            // B[k=ks*32+quad*8+j][n=nt*16+l15]
            short8 b = *(const short8*)&lds_wt[(nt * 16 + l15) * LDSPAD + ks * 32 + quad * 8];
            acc[nt] = __builtin_amdgcn_mfma_f32_16x16x32_bf16(a, b, acc[nt], 0, 0, 0);
        }
    }

    #pragma unroll
    for (int nt = 0; nt < 4; ++nt) {
        int col = nt * 16 + l15;
        float bv = bias[col];
        #pragma unroll
        for (int r = 0; r < 4; ++r) {
            int row = r0 + quad * 4 + r;    // D: row=quad*4+reg, col=lane&15 (+16*nt)
            if (row < nrows) {
                Wh[(size_t)row * OUTF + col] = f2b(acc[nt][r] + bv);
            }
        }
    }
}

// ---- degree count ----
__global__ __launch_bounds__(256) void count_deg(const int* __restrict__ dst,
                                                 int* __restrict__ deg, int n) {
    int i = blockIdx.x * 256 + threadIdx.x;
    if (i < n) atomicAdd(&deg[dst[i]], 1);
}

// ---- single-block exclusive scan (tree scan over 1024 partials) ----
__global__ __launch_bounds__(1024) void scan_deg(const int* __restrict__ deg,
                                                 int* __restrict__ off,
                                                 int* __restrict__ cursor, int n) {
    __shared__ int sums[1024];
    int t = threadIdx.x;
    int chunk = (n + 1023) / 1024;
    int lo = t * chunk;
    int hi = lo + chunk; if (hi > n) hi = n;
    int s = 0;
    for (int i = lo; i < hi; ++i) s += deg[i];
    int own = s;
    sums[t] = s;
    __syncthreads();
    // Hillis-Steele inclusive scan, log2(1024)=10 steps
    for (int ofs = 1; ofs < 1024; ofs <<= 1) {
        int v = 0;
        if (t >= ofs) v = sums[t - ofs];
        __syncthreads();
        if (t >= ofs) sums[t] += v;
        __syncthreads();
    }
    int run = sums[t] - own;   // exclusive offset for this thread's chunk
    if (t == 1023) off[n] = sums[1023];
    for (int i = lo; i < hi; ++i) { off[i] = run; cursor[i] = run; run += deg[i]; }
}

// ---- scatter: group edge src ids by dst ----
__global__ __launch_bounds__(256) void scatter_edges(const int* __restrict__ src,
                                                     const int* __restrict__ dst,
                                                     int* __restrict__ cursor,
                                                     int* __restrict__ perm_src, int n) {
    int i = blockIdx.x * 256 + threadIdx.x;
    if (i < n) {
        int p = atomicAdd(&cursor[dst[i]], 1);
        perm_src[p] = src[i];
    }
}

// ---- gather-mean: one wave per dst node, lane = feature; f32 out ----
__global__ __launch_bounds__(256) void gather_mean(const u16* __restrict__ Wh,
                                                   const int* __restrict__ off,
                                                   const int* __restrict__ perm_src,
                                                   float* __restrict__ out,
                                                   int nnodes) {
    int wave = threadIdx.x >> 6, lane = threadIdx.x & 63;
    int d = blockIdx.x * 4 + wave;
    if (d >= nnodes) return;
    int e0 = off[d], e1 = off[d + 1];
    float acc = 0.0f;
    for (int j = e0; j < e1; ++j) {
        int s = perm_src[j];   // wave-uniform
        acc += __bfloat162float(((const __hip_bfloat16*)Wh)[(size_t)s * OUTF + lane]);
    }
    float deg = (float)(e1 - e0);
    float dv = deg > 1.0f ? deg : 1.0f;
    out[(size_t)d * OUTF + lane] = acc / dv;
}

extern "C" void kernel_launch(void* const* d_in, const int* in_sizes, int n_in,
                              void* d_out, int out_size, void* d_ws, size_t ws_size,
                              hipStream_t stream) {
    const float* user_feats  = (const float*)d_in[0];
    const float* photo_feats = (const float*)d_in[1];
    const float* W_likes     = (const float*)d_in[2];
    const float* b_likes     = (const float*)d_in[3];
    const float* W_likedby   = (const float*)d_in[4];
    const float* b_likedby   = (const float*)d_in[5];
    const int* likes_src     = (const int*)d_in[6];
    const int* likes_dst     = (const int*)d_in[7];
    const int* likedby_src   = (const int*)d_in[8];
    const int* likedby_dst   = (const int*)d_in[9];

    char* ws = (char*)d_ws;
    // total workspace usage: ~50.1 MB
    u16* Wh_likes     = (u16*)(ws + 0);          // 100000*64*2 = 12,800,000
    u16* Wh_likedby   = (u16*)(ws + 12800000);   // 200000*64*2 = 25,600,000
    u16* Wt_likes     = (u16*)(ws + 38400000);   // 32,768
    u16* Wt_likedby   = (u16*)(ws + 38432768);   // 32,768
    int* deg_photo    = (int*)(ws + 38465536);   // 800,000   } zeroed below
    int* deg_user     = (int*)(ws + 39265536);   // 400,000   }
    int* off_photo    = (int*)(ws + 39665536);   // 800,004
    int* off_user     = (int*)(ws + 40465540);   // 400,004
    int* cursor_photo = (int*)(ws + 40865544);   // 800,000
    int* cursor_user  = (int*)(ws + 41665544);   // 400,000
    int* perm_likes   = (int*)(ws + 42065544);   // 4,000,000
    int* perm_likedby = (int*)(ws + 46065544);   // 4,000,000  -> end 50,065,544

    hipMemsetAsync(ws + 38465536, 0, 1200000, stream);  // deg_photo + deg_user

    transpose_w<<<64, 256, 0, stream>>>(W_likes, Wt_likes);
    transpose_w<<<64, 256, 0, stream>>>(W_likedby, Wt_likedby);

    proj_gemm<<<(N_USER + 63) / 64, 256, 0, stream>>>(user_feats, Wt_likes, b_likes,
                                                      Wh_likes, N_USER);
    proj_gemm<<<(N_PHOTO + 63) / 64, 256, 0, stream>>>(photo_feats, Wt_likedby, b_likedby,
                                                       Wh_likedby, N_PHOTO);

    count_deg<<<(NEDGE + 255) / 256, 256, 0, stream>>>(likes_dst, deg_photo, NEDGE);
    count_deg<<<(NEDGE + 255) / 256, 256, 0, stream>>>(likedby_dst, deg_user, NEDGE);

    scan_deg<<<1, 1024, 0, stream>>>(deg_photo, off_photo, cursor_photo, N_PHOTO);
    scan_deg<<<1, 1024, 0, stream>>>(deg_user, off_user, cursor_user, N_USER);

    scatter_edges<<<(NEDGE + 255) / 256, 256, 0, stream>>>(likes_src, likes_dst,
                                                           cursor_photo, perm_likes, NEDGE);
    scatter_edges<<<(NEDGE + 255) / 256, 256, 0, stream>>>(likedby_src, likedby_dst,
                                                           cursor_user, perm_likedby, NEDGE);

    gather_mean<<<(N_PHOTO + 3) / 4, 256, 0, stream>>>(
        Wh_likes, off_photo, perm_likes,
        (float*)d_out + (size_t)N_USER * OUTF, N_PHOTO);
    gather_mean<<<(N_USER + 3) / 4, 256, 0, stream>>>(
        Wh_likedby, off_user, perm_likedby,
        (float*)d_out, N_USER);
}

// Round 4
// 831.987 us; speedup vs baseline: 1.7910x; 1.7910x over previous
//
#include <hip/hip_runtime.h>
#include <hip/hip_bf16.h>

#define N_USER 100000
#define N_PHOTO 200000
#define NEDGE 1000000
#define INF 256
#define OUTF 64

typedef unsigned short u16;
typedef __attribute__((ext_vector_type(8))) short short8;
typedef __attribute__((ext_vector_type(4))) float f32x4;

#define LDSPAD 264  // 256 + 8 pad: keeps 16B alignment, breaks pow2 bank stride
#define SCAN_CHUNK 2048  // ints per block in the hierarchical scan (256 thr x 2 int4)

// f32 -> bf16 bits, round-to-nearest-even
__device__ inline u16 f2b(float f) {
    union { float f; unsigned u; } v; v.f = f;
    unsigned r = v.u + 0x7FFF + ((v.u >> 16) & 1);
    return (u16)(r >> 16);
}

// ---- W[256][64] f32 -> Wt[64][256] bf16 ----
__global__ __launch_bounds__(256) void transpose_w(const float* __restrict__ W,
                                                   u16* __restrict__ Wt) {
    int idx = blockIdx.x * 256 + threadIdx.x;   // 16384 total
    if (idx < INF * OUTF) {
        int n = idx & (OUTF - 1);
        int k = idx >> 6;
        Wt[n * INF + k] = f2b(W[idx]);
    }
}

// ---- Wh = feats @ W + b; f32 feats in, bf16 MFMA, bf16 Wh out ----
__global__ __launch_bounds__(256) void proj_gemm(const float* __restrict__ feats,
                                                 const u16* __restrict__ Wt,
                                                 const float* __restrict__ bias,
                                                 u16* __restrict__ Wh,
                                                 int nrows) {
    __shared__ u16 lds_wt[OUTF * LDSPAD];   // 33792 B
    int tid = threadIdx.x;
    for (int c = tid; c < (INF * OUTF) / 8; c += 256) {
        int n = c >> 5;
        int ko = (c & 31) * 8;
        *(short8*)&lds_wt[n * LDSPAD + ko] = *(const short8*)&Wt[n * INF + ko];
    }
    __syncthreads();

    int wave = tid >> 6, lane = tid & 63;
    int l15 = lane & 15, quad = lane >> 4;
    int r0 = blockIdx.x * 64 + wave * 16;
    int arow = r0 + l15;
    bool arow_ok = arow < nrows;

    f32x4 acc[4] = {{0,0,0,0},{0,0,0,0},{0,0,0,0},{0,0,0,0}};
    const float4* ap = (const float4*)(feats + (size_t)(arow_ok ? arow : 0) * INF);

    #pragma unroll
    for (int ks = 0; ks < 8; ++ks) {
        float4 x = ap[ks * 8 + quad * 2 + 0];   // A[m=arow][k=ks*32+quad*8+j]
        float4 y = ap[ks * 8 + quad * 2 + 1];
        short8 a = { (short)f2b(x.x), (short)f2b(x.y), (short)f2b(x.z), (short)f2b(x.w),
                     (short)f2b(y.x), (short)f2b(y.y), (short)f2b(y.z), (short)f2b(y.w) };
        #pragma unroll
        for (int nt = 0; nt < 4; ++nt) {
            short8 b = *(const short8*)&lds_wt[(nt * 16 + l15) * LDSPAD + ks * 32 + quad * 8];
            acc[nt] = __builtin_amdgcn_mfma_f32_16x16x32_bf16(a, b, acc[nt], 0, 0, 0);
        }
    }

    #pragma unroll
    for (int nt = 0; nt < 4; ++nt) {
        int col = nt * 16 + l15;
        float bv = bias[col];
        #pragma unroll
        for (int r = 0; r < 4; ++r) {
            int row = r0 + quad * 4 + r;    // D: row=quad*4+reg, col=lane&15 (+16*nt)
            if (row < nrows) {
                Wh[(size_t)row * OUTF + col] = f2b(acc[nt][r] + bv);
            }
        }
    }
}

// ---- degree count ----
__global__ __launch_bounds__(256) void count_deg(const int* __restrict__ dst,
                                                 int* __restrict__ deg, int n) {
    int i = blockIdx.x * 256 + threadIdx.x;
    if (i < n) atomicAdd(&deg[dst[i]], 1);
}

// ==== hierarchical exclusive scan (replaces single-block scan_deg: 457us -> ~us) ====

// level 1: per-block sum of a 2048-int chunk (int4 coalesced)
__global__ __launch_bounds__(256) void block_sums(const int* __restrict__ deg,
                                                  int* __restrict__ bsums, int n) {
    __shared__ int lds[256];
    int b = blockIdx.x, t = threadIdx.x;
    int s = 0;
    #pragma unroll
    for (int tile = 0; tile < 2; ++tile) {
        int i4 = b * 512 + tile * 256 + t;
        if (i4 * 4 < n) { int4 v = ((const int4*)deg)[i4]; s += v.x + v.y + v.z + v.w; }
    }
    lds[t] = s;
    __syncthreads();
    for (int ofs = 128; ofs > 0; ofs >>= 1) {
        if (t < ofs) lds[t] += lds[t + ofs];
        __syncthreads();
    }
    if (t == 0) bsums[b] = lds[0];
}

// level 2: exclusive scan of <=256 block sums (in LDS), writes off[n]=total
__global__ __launch_bounds__(256) void scan_blocks(int* __restrict__ bsums,
                                                   int* __restrict__ off, int nb, int n) {
    __shared__ int lds[256];
    int t = threadIdx.x;
    lds[t] = (t < nb) ? bsums[t] : 0;
    __syncthreads();
    if (t == 0) {
        int run = 0;
        for (int i = 0; i < nb; ++i) { int v = lds[i]; lds[i] = run; run += v; }
        off[n] = run;
    }
    __syncthreads();
    if (t < nb) bsums[t] = lds[t];
}

// level 3: per-block local scan + base, writes off and cursor (int4 coalesced)
__global__ __launch_bounds__(256) void scan_apply(const int* __restrict__ deg,
                                                  const int* __restrict__ bbase,
                                                  int* __restrict__ off,
                                                  int* __restrict__ cursor, int n) {
    __shared__ int lds[256];
    int b = blockIdx.x, t = threadIdx.x;
    int base = bbase[b];
    #pragma unroll
    for (int tile = 0; tile < 2; ++tile) {
        int i4 = b * 512 + tile * 256 + t;
        int4 v = {0, 0, 0, 0};
        bool ok = i4 * 4 < n;
        if (ok) v = ((const int4*)deg)[i4];
        int s4 = v.x + v.y + v.z + v.w;
        lds[t] = s4;
        __syncthreads();
        for (int ofs = 1; ofs < 256; ofs <<= 1) {
            int vv = (t >= ofs) ? lds[t - ofs] : 0;
            __syncthreads();
            lds[t] += vv;
            __syncthreads();
        }
        int excl = base + lds[t] - s4;
        if (ok) {
            int4 o;
            o.x = excl; o.y = o.x + v.x; o.z = o.y + v.y; o.w = o.z + v.z;
            ((int4*)off)[i4] = o;
            ((int4*)cursor)[i4] = o;
        }
        base += lds[255];   // tile total
        __syncthreads();    // lds reused next tile
    }
}

// ---- scatter: group edge src ids by dst ----
__global__ __launch_bounds__(256) void scatter_edges(const int* __restrict__ src,
                                                     const int* __restrict__ dst,
                                                     int* __restrict__ cursor,
                                                     int* __restrict__ perm_src, int n) {
    int i = blockIdx.x * 256 + threadIdx.x;
    if (i < n) {
        int p = atomicAdd(&cursor[dst[i]], 1);
        perm_src[p] = src[i];
    }
}

// ---- gather-mean: one wave per dst node, lane = feature; f32 out ----
__global__ __launch_bounds__(256) void gather_mean(const u16* __restrict__ Wh,
                                                   const int* __restrict__ off,
                                                   const int* __restrict__ perm_src,
                                                   float* __restrict__ out,
                                                   int nnodes) {
    int wave = threadIdx.x >> 6, lane = threadIdx.x & 63;
    int d = blockIdx.x * 4 + wave;
    if (d >= nnodes) return;
    int e0 = off[d], e1 = off[d + 1];
    float acc = 0.0f;
    for (int j = e0; j < e1; ++j) {
        int s = perm_src[j];   // wave-uniform
        acc += __bfloat162float(((const __hip_bfloat16*)Wh)[(size_t)s * OUTF + lane]);
    }
    float deg = (float)(e1 - e0);
    float dv = deg > 1.0f ? deg : 1.0f;
    out[(size_t)d * OUTF + lane] = acc / dv;
}

extern "C" void kernel_launch(void* const* d_in, const int* in_sizes, int n_in,
                              void* d_out, int out_size, void* d_ws, size_t ws_size,
                              hipStream_t stream) {
    const float* user_feats  = (const float*)d_in[0];
    const float* photo_feats = (const float*)d_in[1];
    const float* W_likes     = (const float*)d_in[2];
    const float* b_likes     = (const float*)d_in[3];
    const float* W_likedby   = (const float*)d_in[4];
    const float* b_likedby   = (const float*)d_in[5];
    const int* likes_src     = (const int*)d_in[6];
    const int* likes_dst     = (const int*)d_in[7];
    const int* likedby_src   = (const int*)d_in[8];
    const int* likedby_dst   = (const int*)d_in[9];

    char* ws = (char*)d_ws;
    // all offsets 16B-aligned; total ~50.1 MB
    u16* Wh_likes     = (u16*)(ws + 0);          // 12,800,000
    u16* Wh_likedby   = (u16*)(ws + 12800000);   // 25,600,000
    u16* Wt_likes     = (u16*)(ws + 38400000);   // 32,768
    u16* Wt_likedby   = (u16*)(ws + 38432768);   // 32,768
    int* deg_photo    = (int*)(ws + 38465536);   // 800,000   } zeroed below
    int* deg_user     = (int*)(ws + 39265536);   // 400,000   }
    int* off_photo    = (int*)(ws + 39665536);   // 800,016
    int* off_user     = (int*)(ws + 40465552);   // 400,016
    int* cursor_photo = (int*)(ws + 40865568);   // 800,000
    int* cursor_user  = (int*)(ws + 41665568);   // 400,000
    int* perm_likes   = (int*)(ws + 42065568);   // 4,000,000
    int* perm_likedby = (int*)(ws + 46065568);   // 4,000,000
    int* bsums_photo  = (int*)(ws + 50065568);   // 512
    int* bsums_user   = (int*)(ws + 50066080);   // 512 -> end 50,066,592

    const int nb_photo = (N_PHOTO + SCAN_CHUNK - 1) / SCAN_CHUNK;  // 98
    const int nb_user  = (N_USER  + SCAN_CHUNK - 1) / SCAN_CHUNK;  // 49

    hipMemsetAsync(ws + 38465536, 0, 1200000, stream);  // deg_photo + deg_user

    transpose_w<<<64, 256, 0, stream>>>(W_likes, Wt_likes);
    transpose_w<<<64, 256, 0, stream>>>(W_likedby, Wt_likedby);

    proj_gemm<<<(N_USER + 63) / 64, 256, 0, stream>>>(user_feats, Wt_likes, b_likes,
                                                      Wh_likes, N_USER);
    proj_gemm<<<(N_PHOTO + 63) / 64, 256, 0, stream>>>(photo_feats, Wt_likedby, b_likedby,
                                                       Wh_likedby, N_PHOTO);

    count_deg<<<(NEDGE + 255) / 256, 256, 0, stream>>>(likes_dst, deg_photo, NEDGE);
    count_deg<<<(NEDGE + 255) / 256, 256, 0, stream>>>(likedby_dst, deg_user, NEDGE);

    block_sums<<<nb_photo, 256, 0, stream>>>(deg_photo, bsums_photo, N_PHOTO);
    block_sums<<<nb_user,  256, 0, stream>>>(deg_user,  bsums_user,  N_USER);
    scan_blocks<<<1, 256, 0, stream>>>(bsums_photo, off_photo, nb_photo, N_PHOTO);
    scan_blocks<<<1, 256, 0, stream>>>(bsums_user,  off_user,  nb_user,  N_USER);
    scan_apply<<<nb_photo, 256, 0, stream>>>(deg_photo, bsums_photo, off_photo,
                                             cursor_photo, N_PHOTO);
    scan_apply<<<nb_user,  256, 0, stream>>>(deg_user,  bsums_user,  off_user,
                                             cursor_user, N_USER);

    scatter_edges<<<(NEDGE + 255) / 256, 256, 0, stream>>>(likes_src, likes_dst,
                                                           cursor_photo, perm_likes, NEDGE);
    scatter_edges<<<(NEDGE + 255) / 256, 256, 0, stream>>>(likedby_src, likedby_dst,
                                                           cursor_user, perm_likedby, NEDGE);

    gather_mean<<<(N_PHOTO + 3) / 4, 256, 0, stream>>>(
        Wh_likes, off_photo, perm_likes,
        (float*)d_out + (size_t)N_USER * OUTF, N_PHOTO);
    gather_mean<<<(N_USER + 3) / 4, 256, 0, stream>>>(
        Wh_likedby, off_user, perm_likedby,
        (float*)d_out, N_USER);
}